// Round 1
// baseline (3703.781 us; speedup 1.0000x reference)
//
#include <hip/hip_runtime.h>
#include <math.h>

#define HW   65536     // 256*256
#define EPSF 1e-5f

// ---------------------------------------------------------------------------
// K1: BN1 + horizontal passes of the three separable dw convs (1x7, 1x11, 1x21)
// one block = one row (256 px), grid = nimg*64*256 rows
// ---------------------------------------------------------------------------
__global__ __launch_bounds__(256) void k_bn_horiz(
    const float* __restrict__ x,
    const float* __restrict__ g1, const float* __restrict__ b1,
    const float* __restrict__ m1, const float* __restrict__ v1,
    const float* __restrict__ w17a, const float* __restrict__ b17a,
    const float* __restrict__ w111a, const float* __restrict__ b111a,
    const float* __restrict__ w211a, const float* __restrict__ b211a,
    float* __restrict__ t7, float* __restrict__ t11, float* __restrict__ t21)
{
    const int row = blockIdx.x;            // (b*64 + c)*256 + y
    const int tid = threadIdx.x;
    const int c   = (row >> 8) & 63;

    __shared__ float sm[276];              // [0,10) and [266,276) are zero halo
    if (tid < 20) sm[tid < 10 ? tid : 256 + tid] = 0.0f;

    const size_t idx = (size_t)row * 256 + tid;
    const float s1 = g1[c] / sqrtf(v1[c] + EPSF);
    sm[10 + tid] = (x[idx] - m1[c]) * s1 + b1[c];
    __syncthreads();

    float a7 = b17a[c];
#pragma unroll
    for (int k = 0; k < 7; ++k)  a7  += sm[10 + tid + k - 3]  * w17a[c * 7 + k];
    t7[idx] = a7;

    float a11 = b111a[c];
#pragma unroll
    for (int k = 0; k < 11; ++k) a11 += sm[10 + tid + k - 5]  * w111a[c * 11 + k];
    t11[idx] = a11;

    float a21 = b211a[c];
#pragma unroll
    for (int k = 0; k < 21; ++k) a21 += sm[10 + tid + k - 10] * w211a[c * 21 + k];
    t21[idx] = a21;
}

// ---------------------------------------------------------------------------
// K2: 5x5 dw on BN1(x) + vertical passes (7x1, 11x1, 21x1) + sum of branches
// ---------------------------------------------------------------------------
__global__ __launch_bounds__(256) void k_vert_sum(
    const float* __restrict__ x,
    const float* __restrict__ g1, const float* __restrict__ b1,
    const float* __restrict__ m1, const float* __restrict__ v1,
    const float* __restrict__ w55, const float* __restrict__ bb55,
    const float* __restrict__ w17b, const float* __restrict__ b17b,
    const float* __restrict__ w111b, const float* __restrict__ b111b,
    const float* __restrict__ w211b, const float* __restrict__ b211b,
    const float* __restrict__ t7, const float* __restrict__ t11,
    const float* __restrict__ t21,
    float* __restrict__ dsum)
{
    const int row = blockIdx.x;
    const int tid = threadIdx.x;
    const int y     = row & 255;
    const int c     = (row >> 8) & 63;
    const int plane = row >> 8;            // b*64 + c

    const float s1 = g1[c] / sqrtf(v1[c] + EPSF);
    const float mm = m1[c], ab = b1[c];

    const float* xp  = x   + ((size_t)plane << 16);
    const float* p7  = t7  + ((size_t)plane << 16);
    const float* p11 = t11 + ((size_t)plane << 16);
    const float* p21 = t21 + ((size_t)plane << 16);

    float acc = bb55[c] + b17b[c] + b111b[c] + b211b[c];

#pragma unroll
    for (int kh = 0; kh < 5; ++kh) {
        const int yy = y + kh - 2;
        if ((unsigned)yy < 256u) {
#pragma unroll
            for (int kw = 0; kw < 5; ++kw) {
                const int xx = tid + kw - 2;
                if ((unsigned)xx < 256u) {
                    const float n = (xp[yy * 256 + xx] - mm) * s1 + ab;
                    acc += n * w55[c * 25 + kh * 5 + kw];
                }
            }
        }
    }
#pragma unroll
    for (int k = 0; k < 7; ++k)  { const int yy = y + k - 3;  if ((unsigned)yy < 256u) acc += p7 [yy * 256 + tid] * w17b [c * 7 + k]; }
#pragma unroll
    for (int k = 0; k < 11; ++k) { const int yy = y + k - 5;  if ((unsigned)yy < 256u) acc += p11[yy * 256 + tid] * w111b[c * 11 + k]; }
#pragma unroll
    for (int k = 0; k < 21; ++k) { const int yy = y + k - 10; if ((unsigned)yy < 256u) acc += p21[yy * 256 + tid] * w211b[c * 21 + k]; }

    dsum[((size_t)plane << 16) + y * 256 + tid] = acc;
}

// ---------------------------------------------------------------------------
// K3: 1x1 mixer (64x64) + gate with BN1(x) + residual + BN2
// one thread = one pixel (all 64 channels); writes x1 (into d_out) and n2
// ---------------------------------------------------------------------------
__global__ __launch_bounds__(256) void k_mixer(
    const float* __restrict__ x, const float* __restrict__ dsum,
    const float* __restrict__ w11, const float* __restrict__ b11,
    const float* __restrict__ ls1,
    const float* __restrict__ g1, const float* __restrict__ b1,
    const float* __restrict__ m1, const float* __restrict__ v1,
    const float* __restrict__ g2, const float* __restrict__ b2,
    const float* __restrict__ m2, const float* __restrict__ v2,
    float* __restrict__ x1, float* __restrict__ n2)
{
    const int p = blockIdx.x * 256 + threadIdx.x;
    const int b = p >> 16;
    const int s = p & 65535;
    const size_t base = ((size_t)b << 22) + s;     // b*64*HW + s

    float sv[64];
#pragma unroll
    for (int ci = 0; ci < 64; ++ci) sv[ci] = dsum[base + ((size_t)ci << 16)];

    for (int co = 0; co < 64; ++co) {
        float acc = b11[co];
#pragma unroll
        for (int ci = 0; ci < 64; ++ci) acc += w11[co * 64 + ci] * sv[ci];

        const size_t oidx = base + ((size_t)co << 16);
        const float xv  = x[oidx];
        const float n1v = (xv - m1[co]) * (g1[co] / sqrtf(v1[co] + EPSF)) + b1[co];
        const float xo  = xv + ls1[co] * (acc * n1v);
        x1[oidx] = xo;
        n2[oidx] = (xo - m2[co]) * (g2[co] / sqrtf(v2[co] + EPSF)) + b2[co];
    }
}

// ---------------------------------------------------------------------------
// K4: FFN 1x1, 64 -> 256
// ---------------------------------------------------------------------------
__global__ __launch_bounds__(256) void k_pw1(
    const float* __restrict__ n2,
    const float* __restrict__ fw1, const float* __restrict__ fb1,
    float* __restrict__ h1)
{
    const int p = blockIdx.x * 256 + threadIdx.x;
    const int b = p >> 16;
    const int s = p & 65535;
    const size_t ibase = ((size_t)b << 22) + s;

    float iv[64];
#pragma unroll
    for (int ci = 0; ci < 64; ++ci) iv[ci] = n2[ibase + ((size_t)ci << 16)];

    const size_t obase = ((size_t)b << 24) + s;    // b*256*HW + s
    for (int co = 0; co < 256; ++co) {
        float acc = fb1[co];
#pragma unroll
        for (int ci = 0; ci < 64; ++ci) acc += fw1[co * 64 + ci] * iv[ci];
        h1[obase + ((size_t)co << 16)] = acc;
    }
}

// ---------------------------------------------------------------------------
// K5: dw3x3 + exact GELU fused into FFN 1x1 256 -> 64, + residual (in-place on d_out)
// ---------------------------------------------------------------------------
__global__ __launch_bounds__(256) void k_pw2(
    const float* __restrict__ h1,
    const float* __restrict__ fdw, const float* __restrict__ fbdw,
    const float* __restrict__ fw2, const float* __restrict__ fb2,
    const float* __restrict__ ls2,
    float* __restrict__ out)       // holds x1, updated in place
{
    const int p = blockIdx.x * 256 + threadIdx.x;
    const int b = p >> 16;
    const int s = p & 65535;
    const int y  = s >> 8;
    const int xx = s & 255;

    float acc[64];
#pragma unroll
    for (int co = 0; co < 64; ++co) acc[co] = fb2[co];

    for (int ch = 0; ch < 8; ++ch) {           // 8 chunks of 32 input channels
        float hv[32];
#pragma unroll
        for (int j = 0; j < 32; ++j) {
            const int ci = ch * 32 + j;
            const float* hp = h1 + (((size_t)(b * 256 + ci)) << 16);
            float a = fbdw[ci];
#pragma unroll
            for (int dy = -1; dy <= 1; ++dy) {
                const int yy = y + dy;
                if ((unsigned)yy < 256u) {
#pragma unroll
                    for (int dx = -1; dx <= 1; ++dx) {
                        const int xv = xx + dx;
                        if ((unsigned)xv < 256u)
                            a += hp[yy * 256 + xv] * fdw[ci * 9 + (dy + 1) * 3 + (dx + 1)];
                    }
                }
            }
            hv[j] = 0.5f * a * (1.0f + erff(a * 0.70710678118654752f));
        }
#pragma unroll
        for (int co = 0; co < 64; ++co) {
            float t = 0.0f;
#pragma unroll
            for (int j = 0; j < 32; ++j) t += fw2[co * 256 + ch * 32 + j] * hv[j];
            acc[co] += t;
        }
    }

    const size_t obase = ((size_t)b << 22) + s;
#pragma unroll
    for (int co = 0; co < 64; ++co) {
        const size_t oidx = obase + ((size_t)co << 16);
        out[oidx] = out[oidx] + ls2[co] * acc[co];
    }
}

// ---------------------------------------------------------------------------
extern "C" void kernel_launch(void* const* d_in, const int* in_sizes, int n_in,
                              void* d_out, int out_size, void* d_ws, size_t ws_size,
                              hipStream_t stream)
{
    const float* x    = (const float*)d_in[0];
    const float* g1   = (const float*)d_in[1];
    const float* b1   = (const float*)d_in[2];
    const float* m1   = (const float*)d_in[3];
    const float* v1   = (const float*)d_in[4];
    const float* w55  = (const float*)d_in[5];
    const float* bb55 = (const float*)d_in[6];
    const float* w17a = (const float*)d_in[7];
    const float* b17a = (const float*)d_in[8];
    const float* w17b = (const float*)d_in[9];
    const float* b17b = (const float*)d_in[10];
    const float* w111a= (const float*)d_in[11];
    const float* b111a= (const float*)d_in[12];
    const float* w111b= (const float*)d_in[13];
    const float* b111b= (const float*)d_in[14];
    const float* w211a= (const float*)d_in[15];
    const float* b211a= (const float*)d_in[16];
    const float* w211b= (const float*)d_in[17];
    const float* b211b= (const float*)d_in[18];
    const float* w11  = (const float*)d_in[19];
    const float* b11  = (const float*)d_in[20];
    const float* ls1  = (const float*)d_in[21];
    const float* g2   = (const float*)d_in[22];
    const float* b2   = (const float*)d_in[23];
    const float* m2   = (const float*)d_in[24];
    const float* v2   = (const float*)d_in[25];
    const float* fw1  = (const float*)d_in[26];
    const float* fb1  = (const float*)d_in[27];
    const float* fdw  = (const float*)d_in[28];
    const float* fbdw = (const float*)d_in[29];
    const float* fw2  = (const float*)d_in[30];
    const float* fb2  = (const float*)d_in[31];
    const float* ls2  = (const float*)d_in[32];
    float* out = (float*)d_out;

    const size_t IMG = (size_t)64 * HW;     // one image, 64 ch  (4,194,304 elems)
    const size_t TEN = 4 * IMG;             // full batch, 64 ch (16,777,216 elems)
    float* ws = (float*)d_ws;

    // full-batch path needs 5*TEN floats (320 MiB): t7,t11,t21,dsum live then
    // h1 (4*TEN) overlays [0,4*TEN) while n2 sits at [4*TEN,5*TEN)
    const bool full = ws_size >= 5 * TEN * sizeof(float);
    const int  nIter = full ? 1 : 4;
    const int  nimg  = full ? 4 : 1;
    const size_t U   = full ? TEN : IMG;

    for (int it = 0; it < nIter; ++it) {
        const float* xs  = x   + (size_t)it * IMG;
        float*       oss = out + (size_t)it * IMG;
        float* t7   = ws;
        float* t11  = ws + U;
        float* t21  = ws + 2 * U;
        float* dsum = ws + 3 * U;
        float* n2b  = ws + 4 * U;
        float* h1   = ws;                    // overlays t7..dsum (dead by then)

        const int rows = nimg * 64 * 256;    // blocks for row-parallel kernels
        const int pixb = nimg * HW / 256;    // blocks for pixel-parallel kernels

        k_bn_horiz<<<rows, 256, 0, stream>>>(xs, g1, b1, m1, v1,
                                             w17a, b17a, w111a, b111a, w211a, b211a,
                                             t7, t11, t21);
        k_vert_sum<<<rows, 256, 0, stream>>>(xs, g1, b1, m1, v1,
                                             w55, bb55, w17b, b17b,
                                             w111b, b111b, w211b, b211b,
                                             t7, t11, t21, dsum);
        k_mixer<<<pixb, 256, 0, stream>>>(xs, dsum, w11, b11, ls1,
                                          g1, b1, m1, v1, g2, b2, m2, v2,
                                          oss, n2b);
        k_pw1<<<pixb, 256, 0, stream>>>(n2b, fw1, fb1, h1);
        k_pw2<<<pixb, 256, 0, stream>>>(h1, fdw, fbdw, fw2, fb2, ls2, oss);
    }
}